// Round 1
// baseline (3125.442 us; speedup 1.0000x reference)
//
#include <hip/hip_runtime.h>

#define NN 50000
#define NE 800000
#define POOL_BLOCKS 512
#define GN 32   // nodes per gemm block

__device__ __forceinline__ float elu_f(float x){ return x > 0.f ? x : __expf(x) - 1.f; }

__device__ __forceinline__ void atomAddF(float* p, float v){
    __hip_atomic_fetch_add(p, v, __ATOMIC_RELAXED, __HIP_MEMORY_SCOPE_AGENT);
}

__device__ __forceinline__ void fma4(float4& a, float s, const float4& w){
    a.x += s*w.x; a.y += s*w.y; a.z += s*w.z; a.w += s*w.w;
}

// ---- layer 1: scatter 3-channel messages ----
__global__ void k_scatter3(const float* __restrict__ x, const int* __restrict__ row,
                           const int* __restrict__ col, const float* __restrict__ dis,
                           float* __restrict__ agg){
    int e = blockIdx.x * blockDim.x + threadIdx.x;
    if (e >= NE) return;
    int r = row[e], c = col[e];
    float nrm = dis[r] * dis[c];
    atomAddF(&agg[c*3+0], x[r*3+0]*nrm);
    atomAddF(&agg[c*3+1], x[r*3+1]*nrm);
    atomAddF(&agg[c*3+2], x[r*3+2]*nrm);
}

// ---- layer 1 dense: [N,3] @ W1[128,3]^T + b1, ELU ----
__global__ void k_dense3(const float* __restrict__ agg, const float* __restrict__ W,
                         const float* __restrict__ b, float* __restrict__ h){
    int t = blockIdx.x * blockDim.x + threadIdx.x;
    if (t >= NN*128) return;
    int n = t >> 7, j = t & 127;
    float v = fmaf(agg[n*3+0], W[j*3+0],
             fmaf(agg[n*3+1], W[j*3+1],
             fmaf(agg[n*3+2], W[j*3+2], b[j])));
    h[t] = elu_f(v);
}

// ---- channel pooling: per-block partial sum & max over node rows ----
__global__ void k_pool(const float* __restrict__ h, float* __restrict__ part){
    int c = threadIdx.x;           // 128 threads = channels
    int bpr = (NN + POOL_BLOCKS - 1) / POOL_BLOCKS;
    int r0 = blockIdx.x * bpr;
    int r1 = min(r0 + bpr, NN);
    float s = 0.f, m = -3.4e38f;
    for (int r = r0; r < r1; ++r){
        float v = h[(size_t)r*128 + c];
        s += v; m = fmaxf(m, v);
    }
    part[blockIdx.x*128 + c] = s;
    part[POOL_BLOCKS*128 + blockIdx.x*128 + c] = m;
}

// ---- channel attention MLP: att = sigmoid(mlp(avg)+mlp(max)) ----
__global__ void k_attn(const float* __restrict__ part, const float* __restrict__ w1,
                       const float* __restrict__ w2, float* __restrict__ att){
    __shared__ float avg[128], mx[128], ha[8], hm[8];
    int c = threadIdx.x;           // 128 threads
    float s = 0.f, m = -3.4e38f;
    for (int b = 0; b < POOL_BLOCKS; ++b){
        s += part[b*128 + c];
        m = fmaxf(m, part[POOL_BLOCKS*128 + b*128 + c]);
    }
    avg[c] = s / (float)NN;
    mx[c] = m;
    __syncthreads();
    if (c < 8){
        float sa = 0.f, sm = 0.f;
        for (int k = 0; k < 128; ++k){
            float w = w1[c*128 + k];
            sa += avg[k]*w; sm += mx[k]*w;
        }
        ha[c] = fmaxf(sa, 0.f); hm[c] = fmaxf(sm, 0.f);
    }
    __syncthreads();
    float oa = 0.f, om = 0.f;
    for (int j = 0; j < 8; ++j){
        float w = w2[c*8 + j];
        oa += ha[j]*w; om += hm[j]*w;
    }
    att[c] = 1.f / (1.f + __expf(-(oa + om)));
}

// ---- 128-channel scatter: agg[col] += h[row] * att * norm ----
// 32 threads per edge, 4 channels (float4) per thread
__global__ void k_scatter128(const float* __restrict__ h, const int* __restrict__ row,
                             const int* __restrict__ col, const float* __restrict__ dis,
                             const float* __restrict__ att, float* __restrict__ agg){
    unsigned t = blockIdx.x * blockDim.x + threadIdx.x;
    int e = t >> 5, l = t & 31;
    int r = row[e], c = col[e];
    float nrm = dis[r] * dis[c];
    float4 v = ((const float4*)(h + (size_t)r*128))[l];
    float4 a = ((const float4*)att)[l];
    float* dst = agg + (size_t)c*128 + l*4;
    atomAddF(dst+0, v.x*a.x*nrm);
    atomAddF(dst+1, v.y*a.y*nrm);
    atomAddF(dst+2, v.z*a.z*nrm);
    atomAddF(dst+3, v.w*a.w*nrm);
}

// ---- dense: out = ELU(A @ W^T + b), A [N,128], W [128,128] ----
// W transposed into LDS with XOR-ish rotation swizzle to kill stride-128 conflicts
__global__ __launch_bounds__(256) void k_gemm128(const float* __restrict__ A, const float* __restrict__ W,
                         const float* __restrict__ b, float* __restrict__ out){
    __shared__ float4 WtV[128*32];   // WtV[cc*32 + ((jg+cc)&31)] = {W[jg*4+0..3][cc]}
    __shared__ float At[GN*128];
    int tid = threadIdx.x;
    float* Wt = (float*)WtV;
    for (int i = tid; i < 128*128; i += 256){
        int j = i >> 7, cc = i & 127;
        int slot = (cc*32 + (((j>>2) + cc) & 31))*4 + (j&3);
        Wt[slot] = W[i];
    }
    int n0 = blockIdx.x * GN;
    for (int i = tid; i < GN*128; i += 256){
        int n = n0 + (i >> 7);
        At[i] = (n < NN) ? A[(size_t)n*128 + (i & 127)] : 0.f;
    }
    __syncthreads();
    int jg = tid & 31, ng = tid >> 5;   // 4 j's (jg*4..+3), 4 nodes (ng*4..+3)
    float4 bv = ((const float4*)b)[jg];
    float4 acc0 = bv, acc1 = bv, acc2 = bv, acc3 = bv;
    const float4* A0 = (const float4*)(At + (ng*4+0)*128);
    const float4* A1 = (const float4*)(At + (ng*4+1)*128);
    const float4* A2 = (const float4*)(At + (ng*4+2)*128);
    const float4* A3 = (const float4*)(At + (ng*4+3)*128);
    #pragma unroll 4
    for (int c4 = 0; c4 < 32; ++c4){
        int cb = c4*4;
        float4 w0 = WtV[(cb+0)*32 + ((jg + cb+0)&31)];
        float4 w1 = WtV[(cb+1)*32 + ((jg + cb+1)&31)];
        float4 w2 = WtV[(cb+2)*32 + ((jg + cb+2)&31)];
        float4 w3 = WtV[(cb+3)*32 + ((jg + cb+3)&31)];
        float4 a;
        a = A0[c4]; fma4(acc0,a.x,w0); fma4(acc0,a.y,w1); fma4(acc0,a.z,w2); fma4(acc0,a.w,w3);
        a = A1[c4]; fma4(acc1,a.x,w0); fma4(acc1,a.y,w1); fma4(acc1,a.z,w2); fma4(acc1,a.w,w3);
        a = A2[c4]; fma4(acc2,a.x,w0); fma4(acc2,a.y,w1); fma4(acc2,a.z,w2); fma4(acc2,a.w,w3);
        a = A3[c4]; fma4(acc3,a.x,w0); fma4(acc3,a.y,w1); fma4(acc3,a.z,w2); fma4(acc3,a.w,w3);
    }
    float4 accs[4] = {acc0, acc1, acc2, acc3};
    #pragma unroll
    for (int k = 0; k < 4; ++k){
        int n = n0 + ng*4 + k;
        if (n < NN){
            float4 v = accs[k];
            v.x = elu_f(v.x); v.y = elu_f(v.y); v.z = elu_f(v.z); v.w = elu_f(v.w);
            ((float4*)(out + (size_t)n*128))[jg] = v;
        }
    }
}

// ---- output head: out[n,k] = sum_c h[n,c]*att[c]*Wout[k,c] + bout[k] ----
__global__ void k_out(const float* __restrict__ h, const float* __restrict__ att,
                      const float* __restrict__ Wo, const float* __restrict__ bo,
                      float* __restrict__ out){
    int t = blockIdx.x * blockDim.x + threadIdx.x;
    if (t >= NN*3) return;
    int n = t / 3, k = t - n*3;
    const float4* hv = (const float4*)(h + (size_t)n*128);
    const float4* av = (const float4*)att;
    const float4* wv = (const float4*)(Wo + k*128);
    float acc = bo[k];
    #pragma unroll 8
    for (int i = 0; i < 32; ++i){
        float4 hh = hv[i], aa = av[i], ww = wv[i];
        acc += hh.x*aa.x*ww.x + hh.y*aa.y*ww.y + hh.z*aa.z*ww.z + hh.w*aa.w*ww.w;
    }
    out[t] = acc;
}

extern "C" void kernel_launch(void* const* d_in, const int* in_sizes, int n_in,
                              void* d_out, int out_size, void* d_ws, size_t ws_size,
                              hipStream_t stream) {
    const float* x    = (const float*)d_in[0];
    const int*   ei   = (const int*)d_in[1];
    const int*   row  = ei;
    const int*   col  = ei + NE;
    const float* dis  = (const float*)d_in[2];
    const float* W1   = (const float*)d_in[3];
    const float* b1   = (const float*)d_in[4];
    const float* W2   = (const float*)d_in[5];
    const float* b2   = (const float*)d_in[6];
    const float* W3   = (const float*)d_in[7];
    const float* b3   = (const float*)d_in[8];
    const float* ca1w1= (const float*)d_in[9];
    const float* ca1w2= (const float*)d_in[10];
    const float* ca2w1= (const float*)d_in[11];
    const float* ca2w2= (const float*)d_in[12];
    const float* ca3w1= (const float*)d_in[13];
    const float* ca3w2= (const float*)d_in[14];
    const float* Wout = (const float*)d_in[15];
    const float* bout = (const float*)d_in[16];
    float* out = (float*)d_out;

    float* bufA = (float*)d_ws;                         // [N,128] h
    float* bufB = bufA + (size_t)NN*128;                // [N,128] agg
    float* part = bufB + (size_t)NN*128;                // POOL_BLOCKS*128*2
    float* att1 = part + POOL_BLOCKS*256;
    float* att2 = att1 + 128;
    float* att3 = att2 + 128;

    const int scat_blocks = (NE * 32) / 256;            // 100000
    const int gemm_blocks = (NN + GN - 1) / GN;

    // ---- layer 1 ----
    hipMemsetAsync(bufB, 0, (size_t)NN*3*sizeof(float), stream);
    k_scatter3<<<(NE+255)/256, 256, 0, stream>>>(x, row, col, dis, bufB);
    k_dense3<<<(NN*128)/256, 256, 0, stream>>>(bufB, W1, b1, bufA);
    k_pool<<<POOL_BLOCKS, 128, 0, stream>>>(bufA, part);
    k_attn<<<1, 128, 0, stream>>>(part, ca1w1, ca1w2, att1);

    // ---- layer 2 ----
    hipMemsetAsync(bufB, 0, (size_t)NN*128*sizeof(float), stream);
    k_scatter128<<<scat_blocks, 256, 0, stream>>>(bufA, row, col, dis, att1, bufB);
    k_gemm128<<<gemm_blocks, 256, 0, stream>>>(bufB, W2, b2, bufA);
    k_pool<<<POOL_BLOCKS, 128, 0, stream>>>(bufA, part);
    k_attn<<<1, 128, 0, stream>>>(part, ca2w1, ca2w2, att2);

    // ---- layer 3 ----
    hipMemsetAsync(bufB, 0, (size_t)NN*128*sizeof(float), stream);
    k_scatter128<<<scat_blocks, 256, 0, stream>>>(bufA, row, col, dis, att2, bufB);
    k_gemm128<<<gemm_blocks, 256, 0, stream>>>(bufB, W3, b3, bufA);
    k_pool<<<POOL_BLOCKS, 128, 0, stream>>>(bufA, part);
    k_attn<<<1, 128, 0, stream>>>(part, ca3w1, ca3w2, att3);

    // ---- output head (att3 folded in) ----
    k_out<<<(NN*3 + 255)/256, 256, 0, stream>>>(bufA, att3, Wout, bout, out);
}

// Round 2
// 616.295 us; speedup vs baseline: 5.0713x; 5.0713x over previous
//
#include <hip/hip_runtime.h>

#define NN 50000
#define NE 800000
#define POOL_BLOCKS 512
#define GN 32   // nodes per gemm block
#define SCAN_T 1024

__device__ __forceinline__ float elu_f(float x){ return x > 0.f ? x : __expf(x) - 1.f; }

__device__ __forceinline__ void fma4(float4& a, float s, const float4& w){
    a.x += s*w.x; a.y += s*w.y; a.z += s*w.z; a.w += s*w.w;
}

// ======== CSR build (by destination col) ========
__global__ void k_hist(const int* __restrict__ col, int* __restrict__ deg){
    int e = blockIdx.x * blockDim.x + threadIdx.x;
    if (e >= NE) return;
    atomicAdd(&deg[col[e]], 1);
}

// single-block exclusive scan over deg -> rowptr[NN+1]
__global__ __launch_bounds__(SCAN_T) void k_scan(const int* __restrict__ deg, int* __restrict__ rowptr){
    __shared__ int ssum[SCAN_T];
    int tid = threadIdx.x;
    const int CH = (NN + SCAN_T - 1) / SCAN_T;
    int base = tid * CH;
    int s = 0;
    for (int i = 0; i < CH; ++i){
        int idx = base + i;
        if (idx < NN) s += deg[idx];
    }
    ssum[tid] = s;
    __syncthreads();
    for (int off = 1; off < SCAN_T; off <<= 1){
        int v = 0;
        if (tid >= off) v = ssum[tid - off];
        __syncthreads();
        if (tid >= off) ssum[tid] += v;
        __syncthreads();
    }
    int run = (tid == 0) ? 0 : ssum[tid - 1];   // exclusive prefix of this chunk
    for (int i = 0; i < CH; ++i){
        int idx = base + i;
        if (idx < NN){ rowptr[idx] = run; run += deg[idx]; }
    }
    if (tid == SCAN_T - 1) rowptr[NN] = ssum[SCAN_T - 1];
}

// fill CSR: per edge, store source node + precomputed norm
__global__ void k_fill(const int* __restrict__ row, const int* __restrict__ col,
                       const float* __restrict__ dis, const int* __restrict__ rowptr,
                       int* __restrict__ cursor, int* __restrict__ src, float* __restrict__ nrm){
    int e = blockIdx.x * blockDim.x + threadIdx.x;
    if (e >= NE) return;
    int r = row[e], c = col[e];
    int pos = atomicAdd(&cursor[c], 1);
    int idx = rowptr[c] + pos;
    src[idx] = r;
    nrm[idx] = dis[r] * dis[c];
}

// ======== layer 1: gather 3-channel, thread per node ========
__global__ void k_gather3(const float* __restrict__ x, const int* __restrict__ rowptr,
                          const int* __restrict__ src, const float* __restrict__ nrm,
                          float* __restrict__ agg){
    int n = blockIdx.x * blockDim.x + threadIdx.x;
    if (n >= NN) return;
    int j0 = rowptr[n], j1 = rowptr[n + 1];
    float a0 = 0.f, a1 = 0.f, a2 = 0.f;
    for (int j = j0; j < j1; ++j){
        int r = src[j]; float w = nrm[j];
        a0 = fmaf(x[r*3+0], w, a0);
        a1 = fmaf(x[r*3+1], w, a1);
        a2 = fmaf(x[r*3+2], w, a2);
    }
    agg[n*3+0] = a0; agg[n*3+1] = a1; agg[n*3+2] = a2;
}

// ---- layer 1 dense: [N,3] @ W1[128,3]^T + b1, ELU ----
__global__ void k_dense3(const float* __restrict__ agg, const float* __restrict__ W,
                         const float* __restrict__ b, float* __restrict__ h){
    int t = blockIdx.x * blockDim.x + threadIdx.x;
    if (t >= NN*128) return;
    int n = t >> 7, j = t & 127;
    float v = fmaf(agg[n*3+0], W[j*3+0],
             fmaf(agg[n*3+1], W[j*3+1],
             fmaf(agg[n*3+2], W[j*3+2], b[j])));
    h[t] = elu_f(v);
}

// ======== 128-channel gather: agg[n] = att * sum_j h[src[j]] * nrm[j] ========
// 32 lanes per node, float4 per lane
__global__ __launch_bounds__(256) void k_gather128(const float* __restrict__ h,
                              const int* __restrict__ rowptr, const int* __restrict__ src,
                              const float* __restrict__ nrm, const float* __restrict__ att,
                              float* __restrict__ agg){
    int t = blockIdx.x * blockDim.x + threadIdx.x;
    int n = t >> 5, l = t & 31;
    if (n >= NN) return;
    int j0 = rowptr[n], j1 = rowptr[n + 1];
    float4 acc = {0.f, 0.f, 0.f, 0.f};
    int j = j0;
    for (; j + 1 < j1; j += 2){
        int r0 = src[j], r1 = src[j+1];
        float w0 = nrm[j], w1 = nrm[j+1];
        float4 v0 = ((const float4*)(h + (size_t)r0*128))[l];
        float4 v1 = ((const float4*)(h + (size_t)r1*128))[l];
        fma4(acc, w0, v0);
        fma4(acc, w1, v1);
    }
    if (j < j1){
        int r0 = src[j]; float w0 = nrm[j];
        float4 v0 = ((const float4*)(h + (size_t)r0*128))[l];
        fma4(acc, w0, v0);
    }
    float4 a = ((const float4*)att)[l];
    acc.x *= a.x; acc.y *= a.y; acc.z *= a.z; acc.w *= a.w;
    ((float4*)(agg + (size_t)n*128))[l] = acc;
}

// ---- channel pooling: per-block partial sum & max over node rows ----
__global__ void k_pool(const float* __restrict__ h, float* __restrict__ part){
    int c = threadIdx.x;           // 128 threads = channels
    int bpr = (NN + POOL_BLOCKS - 1) / POOL_BLOCKS;
    int r0 = blockIdx.x * bpr;
    int r1 = min(r0 + bpr, NN);
    float s = 0.f, m = -3.4e38f;
    for (int r = r0; r < r1; ++r){
        float v = h[(size_t)r*128 + c];
        s += v; m = fmaxf(m, v);
    }
    part[blockIdx.x*128 + c] = s;
    part[POOL_BLOCKS*128 + blockIdx.x*128 + c] = m;
}

// ---- channel attention MLP: att = sigmoid(mlp(avg)+mlp(max)) ----
__global__ void k_attn(const float* __restrict__ part, const float* __restrict__ w1,
                       const float* __restrict__ w2, float* __restrict__ att){
    __shared__ float avg[128], mx[128], ha[8], hm[8];
    int c = threadIdx.x;           // 128 threads
    float s = 0.f, m = -3.4e38f;
    for (int b = 0; b < POOL_BLOCKS; ++b){
        s += part[b*128 + c];
        m = fmaxf(m, part[POOL_BLOCKS*128 + b*128 + c]);
    }
    avg[c] = s / (float)NN;
    mx[c] = m;
    __syncthreads();
    if (c < 8){
        float sa = 0.f, sm = 0.f;
        for (int k = 0; k < 128; ++k){
            float w = w1[c*128 + k];
            sa += avg[k]*w; sm += mx[k]*w;
        }
        ha[c] = fmaxf(sa, 0.f); hm[c] = fmaxf(sm, 0.f);
    }
    __syncthreads();
    float oa = 0.f, om = 0.f;
    for (int j = 0; j < 8; ++j){
        float w = w2[c*8 + j];
        oa += ha[j]*w; om += hm[j]*w;
    }
    att[c] = 1.f / (1.f + __expf(-(oa + om)));
}

// ---- dense: out = ELU(A @ W^T + b), A [N,128], W [128,128] ----
__global__ __launch_bounds__(256) void k_gemm128(const float* __restrict__ A, const float* __restrict__ W,
                         const float* __restrict__ b, float* __restrict__ out){
    __shared__ float4 WtV[128*32];   // WtV[cc*32 + rot] swizzled transposed W
    __shared__ float At[GN*128];
    int tid = threadIdx.x;
    float* Wt = (float*)WtV;
    for (int i = tid; i < 128*128; i += 256){
        int j = i >> 7, cc = i & 127;
        int slot = (cc*32 + (((j>>2) + cc) & 31))*4 + (j&3);
        Wt[slot] = W[i];
    }
    int n0 = blockIdx.x * GN;
    for (int i = tid; i < GN*128; i += 256){
        int n = n0 + (i >> 7);
        At[i] = (n < NN) ? A[(size_t)n*128 + (i & 127)] : 0.f;
    }
    __syncthreads();
    int jg = tid & 31, ng = tid >> 5;   // 4 j's (jg*4..+3), 4 nodes (ng*4..+3)
    float4 bv = ((const float4*)b)[jg];
    float4 acc0 = bv, acc1 = bv, acc2 = bv, acc3 = bv;
    const float4* A0 = (const float4*)(At + (ng*4+0)*128);
    const float4* A1 = (const float4*)(At + (ng*4+1)*128);
    const float4* A2 = (const float4*)(At + (ng*4+2)*128);
    const float4* A3 = (const float4*)(At + (ng*4+3)*128);
    #pragma unroll 4
    for (int c4 = 0; c4 < 32; ++c4){
        int cb = c4*4;
        float4 w0 = WtV[(cb+0)*32 + ((jg + cb+0)&31)];
        float4 w1 = WtV[(cb+1)*32 + ((jg + cb+1)&31)];
        float4 w2 = WtV[(cb+2)*32 + ((jg + cb+2)&31)];
        float4 w3 = WtV[(cb+3)*32 + ((jg + cb+3)&31)];
        float4 a;
        a = A0[c4]; fma4(acc0,a.x,w0); fma4(acc0,a.y,w1); fma4(acc0,a.z,w2); fma4(acc0,a.w,w3);
        a = A1[c4]; fma4(acc1,a.x,w0); fma4(acc1,a.y,w1); fma4(acc1,a.z,w2); fma4(acc1,a.w,w3);
        a = A2[c4]; fma4(acc2,a.x,w0); fma4(acc2,a.y,w1); fma4(acc2,a.z,w2); fma4(acc2,a.w,w3);
        a = A3[c4]; fma4(acc3,a.x,w0); fma4(acc3,a.y,w1); fma4(acc3,a.z,w2); fma4(acc3,a.w,w3);
    }
    float4 accs[4] = {acc0, acc1, acc2, acc3};
    #pragma unroll
    for (int k = 0; k < 4; ++k){
        int n = n0 + ng*4 + k;
        if (n < NN){
            float4 v = accs[k];
            v.x = elu_f(v.x); v.y = elu_f(v.y); v.z = elu_f(v.z); v.w = elu_f(v.w);
            ((float4*)(out + (size_t)n*128))[jg] = v;
        }
    }
}

// ---- output head: out[n,k] = sum_c h[n,c]*att[c]*Wout[k,c] + bout[k] ----
__global__ void k_out(const float* __restrict__ h, const float* __restrict__ att,
                      const float* __restrict__ Wo, const float* __restrict__ bo,
                      float* __restrict__ out){
    int t = blockIdx.x * blockDim.x + threadIdx.x;
    if (t >= NN*3) return;
    int n = t / 3, k = t - n*3;
    const float4* hv = (const float4*)(h + (size_t)n*128);
    const float4* av = (const float4*)att;
    const float4* wv = (const float4*)(Wo + k*128);
    float acc = bo[k];
    #pragma unroll 8
    for (int i = 0; i < 32; ++i){
        float4 hh = hv[i], aa = av[i], ww = wv[i];
        acc += hh.x*aa.x*ww.x + hh.y*aa.y*ww.y + hh.z*aa.z*ww.z + hh.w*aa.w*ww.w;
    }
    out[t] = acc;
}

extern "C" void kernel_launch(void* const* d_in, const int* in_sizes, int n_in,
                              void* d_out, int out_size, void* d_ws, size_t ws_size,
                              hipStream_t stream) {
    const float* x    = (const float*)d_in[0];
    const int*   ei   = (const int*)d_in[1];
    const int*   row  = ei;
    const int*   col  = ei + NE;
    const float* dis  = (const float*)d_in[2];
    const float* W1   = (const float*)d_in[3];
    const float* b1   = (const float*)d_in[4];
    const float* W2   = (const float*)d_in[5];
    const float* b2   = (const float*)d_in[6];
    const float* W3   = (const float*)d_in[7];
    const float* b3   = (const float*)d_in[8];
    const float* ca1w1= (const float*)d_in[9];
    const float* ca1w2= (const float*)d_in[10];
    const float* ca2w1= (const float*)d_in[11];
    const float* ca2w2= (const float*)d_in[12];
    const float* ca3w1= (const float*)d_in[13];
    const float* ca3w2= (const float*)d_in[14];
    const float* Wout = (const float*)d_in[15];
    const float* bout = (const float*)d_in[16];
    float* out = (float*)d_out;

    float* bufA = (float*)d_ws;                         // [N,128] h
    float* bufB = bufA + (size_t)NN*128;                // [N,128] agg
    float* part = bufB + (size_t)NN*128;                // POOL_BLOCKS*128*2
    float* att1 = part + POOL_BLOCKS*256;
    float* att2 = att1 + 128;
    float* att3 = att2 + 128;
    float* nrm  = att3 + 128;                           // [NE]
    int*   src  = (int*)(nrm + NE);                     // [NE]
    int*   rowptr = src + NE;                           // [NN+1]
    int*   deg  = rowptr + NN + 1;                      // [NN]
    int*   cursor = deg + NN;                           // [NN]

    const int gemm_blocks = (NN + GN - 1) / GN;
    const int gath_blocks = (NN * 32 + 255) / 256;

    // ---- CSR build (once; reused by all 3 layers) ----
    hipMemsetAsync(deg, 0, (size_t)NN * 2 * sizeof(int), stream);   // deg + cursor
    k_hist<<<(NE+255)/256, 256, 0, stream>>>(col, deg);
    k_scan<<<1, SCAN_T, 0, stream>>>(deg, rowptr);
    k_fill<<<(NE+255)/256, 256, 0, stream>>>(row, col, dis, rowptr, cursor, src, nrm);

    // ---- layer 1 ----
    k_gather3<<<(NN+255)/256, 256, 0, stream>>>(x, rowptr, src, nrm, bufB);
    k_dense3<<<(NN*128)/256, 256, 0, stream>>>(bufB, W1, b1, bufA);
    k_pool<<<POOL_BLOCKS, 128, 0, stream>>>(bufA, part);
    k_attn<<<1, 128, 0, stream>>>(part, ca1w1, ca1w2, att1);

    // ---- layer 2 ----
    k_gather128<<<gath_blocks, 256, 0, stream>>>(bufA, rowptr, src, nrm, att1, bufB);
    k_gemm128<<<gemm_blocks, 256, 0, stream>>>(bufB, W2, b2, bufA);
    k_pool<<<POOL_BLOCKS, 128, 0, stream>>>(bufA, part);
    k_attn<<<1, 128, 0, stream>>>(part, ca2w1, ca2w2, att2);

    // ---- layer 3 ----
    k_gather128<<<gath_blocks, 256, 0, stream>>>(bufA, rowptr, src, nrm, att2, bufB);
    k_gemm128<<<gemm_blocks, 256, 0, stream>>>(bufB, W3, b3, bufA);
    k_pool<<<POOL_BLOCKS, 128, 0, stream>>>(bufA, part);
    k_attn<<<1, 128, 0, stream>>>(part, ca3w1, ca3w2, att3);

    // ---- output head (att3 folded in) ----
    k_out<<<(NN*3 + 255)/256, 256, 0, stream>>>(bufA, att3, Wout, bout, out);
}